// Round 1
// baseline (395.562 us; speedup 1.0000x reference)
//
#include <hip/hip_runtime.h>
#include <math.h>

typedef __attribute__((ext_vector_type(8))) short bf16x8;
typedef __attribute__((ext_vector_type(4))) short bf16x4;
typedef __attribute__((ext_vector_type(4))) float f32x4;

#define MFMA16(a, b, c) __builtin_amdgcn_mfma_f32_16x16x32_bf16(a, b, c, 0, 0, 0)

__device__ __forceinline__ short f2bf(float f) {
    union { float f; unsigned u; } x; x.f = f;
    unsigned r = (x.u + 0x7fffu + ((x.u >> 16) & 1u)) >> 16;
    return (short)r;
}

// ---------------- elementwise fp32 -> bf16 ----------------
__global__ __launch_bounds__(256) void convert_bf16_kernel(
    const float* __restrict__ in, short* __restrict__ out, int n4) {
    int i = blockIdx.x * 256 + threadIdx.x;
    if (i >= n4) return;
    float4 v = ((const float4*)in)[i];
    bf16x4 o;
    o[0] = f2bf(v.x); o[1] = f2bf(v.y); o[2] = f2bf(v.z); o[3] = f2bf(v.w);
    ((bf16x4*)out)[i] = o;
}

// ---------------- transpose + convert: W[K][N] fp32 -> Wt[N][K] bf16 ----------------
__global__ __launch_bounds__(256) void transpose_w_kernel(
    const float* __restrict__ W, short* __restrict__ Wt, int K, int N) {
    __shared__ float tile[32][33];
    int c = threadIdx.x & 31, r0 = threadIdx.x >> 5;
    int n0 = blockIdx.x << 5, k0 = blockIdx.y << 5;
#pragma unroll
    for (int i = 0; i < 4; i++) {
        int r = r0 + i * 8;
        tile[r][c] = W[(long)(k0 + r) * N + n0 + c];
    }
    __syncthreads();
#pragma unroll
    for (int i = 0; i < 4; i++) {
        int r = r0 + i * 8;
        Wt[(long)(n0 + r) * K + k0 + c] = f2bf(tile[c][r]);
    }
}

// ---------------- bf16 GEMM: C = A[M,K] * Bt[N,K]^T + bias ----------------
// EPI 0: fp32 out[M,N].  EPI 1: scatter qkv -> Qb/Kb (B,H,S,hd) and VTb (B,H,hd,S), bf16.
template <int EPI>
__global__ __launch_bounds__(256) void gemm_bt_kernel(
    const short* __restrict__ A, const short* __restrict__ Bt,
    const float* __restrict__ bias, float* __restrict__ outF,
    short* __restrict__ Qb, short* __restrict__ Kb, short* __restrict__ VTb,
    int M, int N, int Kdim) {
    constexpr int BM = 128, BN = 128, BK = 64, LS = BK + 8;  // pad: stride 72 elems
    __shared__ __align__(16) short lsA[BM * LS];
    __shared__ __align__(16) short lsB[BN * LS];
    const int tid = threadIdx.x;
    const int lane = tid & 63, l15 = lane & 15, quad = lane >> 4;
    const int w = tid >> 6, wm = w >> 1, wn = w & 1;
    const int m0 = blockIdx.y * BM, n0 = blockIdx.x * BN;

    f32x4 acc[4][4];
#pragma unroll
    for (int i = 0; i < 4; i++)
#pragma unroll
        for (int j = 0; j < 4; j++) acc[i][j] = (f32x4){0.f, 0.f, 0.f, 0.f};

    for (int k0 = 0; k0 < Kdim; k0 += BK) {
#pragma unroll
        for (int i = 0; i < 4; i++) {
            int c = tid + 256 * i;
            int row = c >> 3, kc = (c & 7) << 3;
            *(bf16x8*)&lsA[row * LS + kc] =
                *(const bf16x8*)&A[(long)(m0 + row) * Kdim + k0 + kc];
            *(bf16x8*)&lsB[row * LS + kc] =
                *(const bf16x8*)&Bt[(long)(n0 + row) * Kdim + k0 + kc];
        }
        __syncthreads();
#pragma unroll
        for (int kk = 0; kk < BK; kk += 32) {
            bf16x8 af[4], bfr[4];
#pragma unroll
            for (int t = 0; t < 4; t++) {
                af[t] = *(const bf16x8*)&lsA[(wm * 64 + t * 16 + l15) * LS + kk + quad * 8];
                bfr[t] = *(const bf16x8*)&lsB[(wn * 64 + t * 16 + l15) * LS + kk + quad * 8];
            }
#pragma unroll
            for (int mt = 0; mt < 4; mt++)
#pragma unroll
                for (int nt = 0; nt < 4; nt++)
                    acc[mt][nt] = MFMA16(af[mt], bfr[nt], acc[mt][nt]);
        }
        __syncthreads();
    }

    // epilogue; C/D layout: row = quad*4 + r, col = l15 within each 16x16 tile
#pragma unroll
    for (int nt = 0; nt < 4; nt++) {
        int nn = n0 + wn * 64 + nt * 16 + l15;
        float bv = bias[nn];
#pragma unroll
        for (int mt = 0; mt < 4; mt++) {
#pragma unroll
            for (int r = 0; r < 4; r++) {
                int mm = m0 + wm * 64 + mt * 16 + quad * 4 + r;
                float val = acc[mt][nt][r] + bv;
                if (EPI == 0) {
                    outF[(long)mm * N + nn] = val;
                } else {
                    int t = nn >> 10, col = nn & 1023, hh = col >> 6, d = col & 63;
                    int b = mm >> 11, s = mm & 2047;
                    int idx = ((b * 16 + hh) * 2048 + s) * 64 + d;
                    if (t == 0) {
                        // fold 1/sqrt(64) * log2(e) so softmax uses exp2
                        Qb[idx] = f2bf(val * 0.18033688011112042f);
                    } else if (t == 1) {
                        Kb[idx] = f2bf(val);
                    } else {
                        VTb[((b * 16 + hh) * 64 + d) * 2048 + s] = f2bf(val);
                    }
                }
            }
        }
    }
}

// ---------------- causal flash attention ----------------
// 1 wave = 16 q rows. Q pre-scaled by 0.125*log2(e). K: [B,H,S,64], VT: [B,H,64,S].
__global__ __launch_bounds__(256) void attn_kernel(
    const short* __restrict__ Q, const short* __restrict__ Kb,
    const short* __restrict__ VT, short* __restrict__ Ao) {
    __shared__ __align__(16) short pbuf[4][16 * 40];
    const int tid = threadIdx.x;
    const int lane = tid & 63, l15 = lane & 15, quad = lane >> 4;
    const int wid = blockIdx.x * 4 + (tid >> 6);
    const int qc = wid & 127, h = (wid >> 7) & 15, b = wid >> 11;
    const int q0 = qc << 4;
    const int headoff = (b * 16 + h) * 2048 * 64;
    const short* Qh = Q + headoff;
    const short* Kh = Kb + headoff;
    const short* Vh = VT + headoff;  // [64][2048]
    short* myp = &pbuf[tid >> 6][0];

    bf16x8 aq0 = *(const bf16x8*)&Qh[(q0 + l15) * 64 + quad * 8];
    bf16x8 aq1 = *(const bf16x8*)&Qh[(q0 + l15) * 64 + 32 + quad * 8];

    float m[4], l[4];
    f32x4 o[4];
#pragma unroll
    for (int r = 0; r < 4; r++) { m[r] = -INFINITY; l[r] = 0.f; }
#pragma unroll
    for (int nt = 0; nt < 4; nt++) o[nt] = (f32x4){0.f, 0.f, 0.f, 0.f};

    for (int kt = 0; kt < q0 + 16; kt += 32) {
        f32x4 sA = (f32x4){0.f, 0.f, 0.f, 0.f}, sB = (f32x4){0.f, 0.f, 0.f, 0.f};
        {
            bf16x8 b0 = *(const bf16x8*)&Kh[(kt + l15) * 64 + quad * 8];
            bf16x8 b1 = *(const bf16x8*)&Kh[(kt + l15) * 64 + 32 + quad * 8];
            sA = MFMA16(aq0, b0, sA);
            sA = MFMA16(aq1, b1, sA);
            bf16x8 b2 = *(const bf16x8*)&Kh[(kt + 16 + l15) * 64 + quad * 8];
            bf16x8 b3 = *(const bf16x8*)&Kh[(kt + 16 + l15) * 64 + 32 + quad * 8];
            sB = MFMA16(aq0, b2, sB);
            sB = MFMA16(aq1, b3, sB);
        }
        if (kt + 31 > q0) {  // only diagonal chunks need masking
#pragma unroll
            for (int r = 0; r < 4; r++) {
                int qr = q0 + quad * 4 + r;
                if (kt + l15 > qr) sA[r] = -INFINITY;
                if (kt + 16 + l15 > qr) sB[r] = -INFINITY;
            }
        }
        float alpha[4];
#pragma unroll
        for (int r = 0; r < 4; r++) {
            float cm = fmaxf(sA[r], sB[r]);
            cm = fmaxf(cm, __shfl_xor(cm, 1));
            cm = fmaxf(cm, __shfl_xor(cm, 2));
            cm = fmaxf(cm, __shfl_xor(cm, 4));
            cm = fmaxf(cm, __shfl_xor(cm, 8));
            float mn = fmaxf(m[r], cm);
            alpha[r] = exp2f(m[r] - mn);
            m[r] = mn;
            float pa = exp2f(sA[r] - mn);
            float pb = exp2f(sB[r] - mn);
            float rs = pa + pb;
            rs += __shfl_xor(rs, 1);
            rs += __shfl_xor(rs, 2);
            rs += __shfl_xor(rs, 4);
            rs += __shfl_xor(rs, 8);
            l[r] = l[r] * alpha[r] + rs;
            // P: C/D layout -> LDS (row = quad*4+r, cols l15 / 16+l15)
            myp[(quad * 4 + r) * 40 + l15] = f2bf(pa);
            myp[(quad * 4 + r) * 40 + 16 + l15] = f2bf(pb);
        }
#pragma unroll
        for (int nt = 0; nt < 4; nt++)
#pragma unroll
            for (int r = 0; r < 4; r++) o[nt][r] *= alpha[r];
        // read back in A-operand layout: m = l15 (q), k = quad*8+j (key)
        bf16x8 ap = *(const bf16x8*)&myp[l15 * 40 + quad * 8];
#pragma unroll
        for (int nt = 0; nt < 4; nt++) {
            bf16x8 bv = *(const bf16x8*)&Vh[(nt * 16 + l15) * 2048 + kt + quad * 8];
            o[nt] = MFMA16(ap, bv, o[nt]);
        }
    }
#pragma unroll
    for (int nt = 0; nt < 4; nt++) {
#pragma unroll
        for (int r = 0; r < 4; r++) {
            int q = q0 + quad * 4 + r;
            Ao[(b * 2048 + q) * 1024 + h * 64 + nt * 16 + l15] = f2bf(o[nt][r] / l[r]);
        }
    }
}

extern "C" void kernel_launch(void* const* d_in, const int* in_sizes, int n_in,
                              void* d_out, int out_size, void* d_ws, size_t ws_size,
                              hipStream_t stream) {
    const float* hs = (const float*)d_in[0];
    const float* W_attn = (const float*)d_in[1];
    const float* b_attn = (const float*)d_in[2];
    const float* W_proj = (const float*)d_in[3];
    const float* b_proj = (const float*)d_in[4];
    float* out = (float*)d_out;

    char* ws = (char*)d_ws;
    short* hs_bf = (short*)ws;                       // 4096x1024 bf16 (8 MB)
    short* attn_o = hs_bf;                           // alias: hs_bf dead after qkv gemm
    short* WaT = (short*)(ws + 8u * 1024 * 1024);    // 3072x1024 bf16 (6 MB)
    short* WpT = (short*)(ws + 14u * 1024 * 1024);   // 1024x1024 bf16 (2 MB)
    short* Qb = (short*)(ws + 16u * 1024 * 1024);    // [2,16,2048,64] bf16 (8 MB)
    short* Kb = (short*)(ws + 24u * 1024 * 1024);    // [2,16,2048,64] bf16 (8 MB)
    short* VTb = (short*)(ws + 32u * 1024 * 1024);   // [2,16,64,2048] bf16 (8 MB)

    convert_bf16_kernel<<<4096, 256, 0, stream>>>(hs, hs_bf, 1048576);
    transpose_w_kernel<<<dim3(96, 32), 256, 0, stream>>>(W_attn, WaT, 1024, 3072);
    transpose_w_kernel<<<dim3(32, 32), 256, 0, stream>>>(W_proj, WpT, 1024, 1024);
    gemm_bt_kernel<1><<<dim3(24, 32), 256, 0, stream>>>(
        hs_bf, WaT, b_attn, nullptr, Qb, Kb, VTb, 4096, 3072, 1024);
    attn_kernel<<<1024, 256, 0, stream>>>(Qb, Kb, VTb, attn_o);
    gemm_bt_kernel<0><<<dim3(8, 32), 256, 0, stream>>>(
        attn_o, WpT, b_proj, out, nullptr, nullptr, nullptr, 4096, 1024, 1024);
}

// Round 2
// 292.627 us; speedup vs baseline: 1.3518x; 1.3518x over previous
//
#include <hip/hip_runtime.h>
#include <math.h>

typedef __attribute__((ext_vector_type(8))) short bf16x8;
typedef __attribute__((ext_vector_type(4))) short bf16x4;
typedef __attribute__((ext_vector_type(4))) float f32x4;

#define MFMA16(a, b, c) __builtin_amdgcn_mfma_f32_16x16x32_bf16(a, b, c, 0, 0, 0)

__device__ __forceinline__ short f2bf(float f) {
    union { float f; unsigned u; } x; x.f = f;
    unsigned r = (x.u + 0x7fffu + ((x.u >> 16) & 1u)) >> 16;
    return (short)r;
}

// ---------------- elementwise fp32 -> bf16 ----------------
__global__ __launch_bounds__(256) void convert_bf16_kernel(
    const float* __restrict__ in, short* __restrict__ out, int n4) {
    int i = blockIdx.x * 256 + threadIdx.x;
    if (i >= n4) return;
    float4 v = ((const float4*)in)[i];
    bf16x4 o;
    o[0] = f2bf(v.x); o[1] = f2bf(v.y); o[2] = f2bf(v.z); o[3] = f2bf(v.w);
    ((bf16x4*)out)[i] = o;
}

// ---------------- transpose + convert: W[K][N] fp32 -> Wt[N][K] bf16 ----------------
__global__ __launch_bounds__(256) void transpose_w_kernel(
    const float* __restrict__ W, short* __restrict__ Wt, int K, int N) {
    __shared__ float tile[32][33];
    int c = threadIdx.x & 31, r0 = threadIdx.x >> 5;
    int n0 = blockIdx.x << 5, k0 = blockIdx.y << 5;
#pragma unroll
    for (int i = 0; i < 4; i++) {
        int r = r0 + i * 8;
        tile[r][c] = W[(long)(k0 + r) * N + n0 + c];
    }
    __syncthreads();
#pragma unroll
    for (int i = 0; i < 4; i++) {
        int r = r0 + i * 8;
        Wt[(long)(n0 + r) * K + k0 + c] = f2bf(tile[c][r]);
    }
}

// ---------------- bf16 GEMM: C = A[M,K] * Bt[N,K]^T + bias ----------------
template <int EPI>
__global__ __launch_bounds__(256) void gemm_bt_kernel(
    const short* __restrict__ A, const short* __restrict__ Bt,
    const float* __restrict__ bias, float* __restrict__ outF,
    short* __restrict__ Qb, short* __restrict__ Kb, short* __restrict__ VTb,
    int M, int N, int Kdim) {
    constexpr int BM = 128, BN = 128, BK = 64, LS = BK + 8;
    __shared__ __align__(16) short lsA[BM * LS];
    __shared__ __align__(16) short lsB[BN * LS];
    const int tid = threadIdx.x;
    const int lane = tid & 63, l15 = lane & 15, quad = lane >> 4;
    const int w = tid >> 6, wm = w >> 1, wn = w & 1;
    const int m0 = blockIdx.y * BM, n0 = blockIdx.x * BN;

    f32x4 acc[4][4];
#pragma unroll
    for (int i = 0; i < 4; i++)
#pragma unroll
        for (int j = 0; j < 4; j++) acc[i][j] = (f32x4){0.f, 0.f, 0.f, 0.f};

    for (int k0 = 0; k0 < Kdim; k0 += BK) {
#pragma unroll
        for (int i = 0; i < 4; i++) {
            int c = tid + 256 * i;
            int row = c >> 3, kc = (c & 7) << 3;
            *(bf16x8*)&lsA[row * LS + kc] =
                *(const bf16x8*)&A[(long)(m0 + row) * Kdim + k0 + kc];
            *(bf16x8*)&lsB[row * LS + kc] =
                *(const bf16x8*)&Bt[(long)(n0 + row) * Kdim + k0 + kc];
        }
        __syncthreads();
#pragma unroll
        for (int kk = 0; kk < BK; kk += 32) {
            bf16x8 af[4], bfr[4];
#pragma unroll
            for (int t = 0; t < 4; t++) {
                af[t] = *(const bf16x8*)&lsA[(wm * 64 + t * 16 + l15) * LS + kk + quad * 8];
                bfr[t] = *(const bf16x8*)&lsB[(wn * 64 + t * 16 + l15) * LS + kk + quad * 8];
            }
#pragma unroll
            for (int mt = 0; mt < 4; mt++)
#pragma unroll
                for (int nt = 0; nt < 4; nt++)
                    acc[mt][nt] = MFMA16(af[mt], bfr[nt], acc[mt][nt]);
        }
        __syncthreads();
    }

#pragma unroll
    for (int nt = 0; nt < 4; nt++) {
        int nn = n0 + wn * 64 + nt * 16 + l15;
        float bv = bias[nn];
#pragma unroll
        for (int mt = 0; mt < 4; mt++) {
#pragma unroll
            for (int r = 0; r < 4; r++) {
                int mm = m0 + wm * 64 + mt * 16 + quad * 4 + r;
                float val = acc[mt][nt][r] + bv;
                if (EPI == 0) {
                    outF[(long)mm * N + nn] = val;
                } else {
                    int t = nn >> 10, col = nn & 1023, hh = col >> 6, d = col & 63;
                    int b = mm >> 11, s = mm & 2047;
                    int idx = ((b * 16 + hh) * 2048 + s) * 64 + d;
                    if (t == 0) {
                        Qb[idx] = f2bf(val * 0.18033688011112042f);  // 1/8 * log2(e)
                    } else if (t == 1) {
                        Kb[idx] = f2bf(val);
                    } else {
                        VTb[((b * 16 + hh) * 64 + d) * 2048 + s] = f2bf(val);
                    }
                }
            }
        }
    }
}

// ---------------- causal flash attention, transposed-score formulation ----------------
// 1 wave (64-thread block) = 16 q rows. Computes S^T = K*Q^T and O^T = V^T*P^T so the
// softmax reduction over keys is in-lane (8 regs) + 2 shuffles, and m/l/alpha are one
// scalar per lane (q = lane&15). K/V fragments register-double-buffered (prefetch).
__global__ __launch_bounds__(64, 4) void attn_kernel(
    const short* __restrict__ Q, const short* __restrict__ Kb,
    const short* __restrict__ VT, short* __restrict__ Ao) {
    __shared__ __align__(16) short Pl[16 * 40];  // [q][key] stride 40, 1.25 KB
    const int lane = threadIdx.x & 63;
    const int l15 = lane & 15, quad = lane >> 4;
    const int wid = blockIdx.x;
    const int qc = 127 - (wid >> 5);   // heavy q-chunks dispatched first
    const int hb = wid & 31;           // b*16 + h
    const int q0 = qc << 4;
    const size_t headoff = (size_t)hb * 2048 * 64;
    const short* Qh = Q + headoff;
    const short* Kh = Kb + headoff;
    const short* Vh = VT + headoff;    // [64][2048]

    // Q as B-operand: n = l15 (q), k = quad*8+j (d)
    bf16x8 qf0 = *(const bf16x8*)&Qh[(q0 + l15) * 64 + quad * 8];
    bf16x8 qf1 = *(const bf16x8*)&Qh[(q0 + l15) * 64 + 32 + quad * 8];

    float m = -INFINITY, l = 0.f;
    f32x4 o[4];
#pragma unroll
    for (int dt = 0; dt < 4; dt++) o[dt] = (f32x4){0.f, 0.f, 0.f, 0.f};

    const int nc = (q0 >> 5) + 1;  // 32-key chunks; last one masked

    // K as A-operand: m = l15 (key row), k = quad*8+j (d); kf[t*2+h]: keytile t, d-half h
    // V^T as A-operand: m = l15 (d within dt tile), k = quad*8+j (key)
    bf16x8 kf[4], vf[4];
#pragma unroll
    for (int t = 0; t < 2; t++) {
        kf[t * 2 + 0] = *(const bf16x8*)&Kh[(t * 16 + l15) * 64 + quad * 8];
        kf[t * 2 + 1] = *(const bf16x8*)&Kh[(t * 16 + l15) * 64 + 32 + quad * 8];
    }
#pragma unroll
    for (int dt = 0; dt < 4; dt++)
        vf[dt] = *(const bf16x8*)&Vh[(dt * 16 + l15) * 2048 + quad * 8];

    for (int c = 0; c < nc; c++) {
        const int kt = c << 5;
        const bool more = (c + 1 < nc);
        bf16x8 nk[4], nv[4];
        if (more) {
            const int k2 = kt + 32;
#pragma unroll
            for (int t = 0; t < 2; t++) {
                nk[t * 2 + 0] = *(const bf16x8*)&Kh[(k2 + t * 16 + l15) * 64 + quad * 8];
                nk[t * 2 + 1] = *(const bf16x8*)&Kh[(k2 + t * 16 + l15) * 64 + 32 + quad * 8];
            }
#pragma unroll
            for (int dt = 0; dt < 4; dt++)
                nv[dt] = *(const bf16x8*)&Vh[(dt * 16 + l15) * 2048 + k2 + quad * 8];
        }

        // S^T = K * Q^T : C/D col = l15 = q, row = quad*4+r = key within tile
        f32x4 s0 = (f32x4){0.f, 0.f, 0.f, 0.f}, s1 = (f32x4){0.f, 0.f, 0.f, 0.f};
        s0 = MFMA16(kf[0], qf0, s0);
        s0 = MFMA16(kf[1], qf1, s0);
        s1 = MFMA16(kf[2], qf0, s1);
        s1 = MFMA16(kf[3], qf1, s1);

        if (c == nc - 1) {  // only the last chunk can cross the diagonal
            const int qq = q0 + l15;
#pragma unroll
            for (int r = 0; r < 4; r++) {
                if (kt + quad * 4 + r > qq) s0[r] = -INFINITY;
                if (kt + 16 + quad * 4 + r > qq) s1[r] = -INFINITY;
            }
        }

        // max over 32 keys: in-lane tree over 8, then across quads (xor 16, 32)
        float cm = fmaxf(fmaxf(fmaxf(s0[0], s0[1]), fmaxf(s0[2], s0[3])),
                         fmaxf(fmaxf(s1[0], s1[1]), fmaxf(s1[2], s1[3])));
        cm = fmaxf(cm, __shfl_xor(cm, 16));
        cm = fmaxf(cm, __shfl_xor(cm, 32));
        const float mn = fmaxf(m, cm);
        const float alpha = __builtin_amdgcn_exp2f(m - mn);
        m = mn;

        float p0[4], p1[4];
#pragma unroll
        for (int r = 0; r < 4; r++) {
            p0[r] = __builtin_amdgcn_exp2f(s0[r] - mn);
            p1[r] = __builtin_amdgcn_exp2f(s1[r] - mn);
        }
        float rs = (p0[0] + p0[1]) + (p0[2] + p0[3]) + (p1[0] + p1[1]) + (p1[2] + p1[3]);
        rs += __shfl_xor(rs, 16);
        rs += __shfl_xor(rs, 32);
        l = l * alpha + rs;

        // P^T -> LDS as [q][key]: lane writes keys t*16+quad*4 .. +3 (contiguous)
        bf16x4 w0, w1;
#pragma unroll
        for (int r = 0; r < 4; r++) { w0[r] = f2bf(p0[r]); w1[r] = f2bf(p1[r]); }
        *(bf16x4*)&Pl[l15 * 40 + quad * 4] = w0;
        *(bf16x4*)&Pl[l15 * 40 + 16 + quad * 4] = w1;

#pragma unroll
        for (int dt = 0; dt < 4; dt++) {
            o[dt][0] *= alpha; o[dt][1] *= alpha; o[dt][2] *= alpha; o[dt][3] *= alpha;
        }

        // P^T as B-operand: n = l15 = q, k = quad*8+j = key (one b128, shared by 4 MFMAs)
        bf16x8 pf = *(const bf16x8*)&Pl[l15 * 40 + quad * 8];
#pragma unroll
        for (int dt = 0; dt < 4; dt++) o[dt] = MFMA16(vf[dt], pf, o[dt]);

        if (more) {
#pragma unroll
            for (int i = 0; i < 4; i++) { kf[i] = nk[i]; vf[i] = nv[i]; }
        }
    }

    // O^T: row = quad*4+r = d within dt tile, col = l15 = q. Lane's 4 r-values contiguous in d.
    const float rl = 1.f / l;
    const int b = hb >> 4, h = hb & 15;
    const long base = ((long)(b * 2048 + q0 + l15)) * 1024 + h * 64;
#pragma unroll
    for (int dt = 0; dt < 4; dt++) {
        bf16x4 w;
#pragma unroll
        for (int r = 0; r < 4; r++) w[r] = f2bf(o[dt][r] * rl);
        *(bf16x4*)&Ao[base + dt * 16 + quad * 4] = w;
    }
}

extern "C" void kernel_launch(void* const* d_in, const int* in_sizes, int n_in,
                              void* d_out, int out_size, void* d_ws, size_t ws_size,
                              hipStream_t stream) {
    const float* hs = (const float*)d_in[0];
    const float* W_attn = (const float*)d_in[1];
    const float* b_attn = (const float*)d_in[2];
    const float* W_proj = (const float*)d_in[3];
    const float* b_proj = (const float*)d_in[4];
    float* out = (float*)d_out;

    char* ws = (char*)d_ws;
    short* hs_bf = (short*)ws;                       // 4096x1024 bf16 (8 MB)
    short* attn_o = hs_bf;                           // alias: hs_bf dead after qkv gemm
    short* WaT = (short*)(ws + 8u * 1024 * 1024);    // 3072x1024 bf16 (6 MB)
    short* WpT = (short*)(ws + 14u * 1024 * 1024);   // 1024x1024 bf16 (2 MB)
    short* Qb = (short*)(ws + 16u * 1024 * 1024);    // [2,16,2048,64] bf16 (8 MB)
    short* Kb = (short*)(ws + 24u * 1024 * 1024);    // [2,16,2048,64] bf16 (8 MB)
    short* VTb = (short*)(ws + 32u * 1024 * 1024);   // [2,16,64,2048] bf16 (8 MB)

    convert_bf16_kernel<<<4096, 256, 0, stream>>>(hs, hs_bf, 1048576);
    transpose_w_kernel<<<dim3(96, 32), 256, 0, stream>>>(W_attn, WaT, 1024, 3072);
    transpose_w_kernel<<<dim3(32, 32), 256, 0, stream>>>(W_proj, WpT, 1024, 1024);
    gemm_bt_kernel<1><<<dim3(24, 32), 256, 0, stream>>>(
        hs_bf, WaT, b_attn, nullptr, Qb, Kb, VTb, 4096, 3072, 1024);
    attn_kernel<<<4096, 64, 0, stream>>>(Qb, Kb, VTb, attn_o);
    gemm_bt_kernel<0><<<dim3(8, 32), 256, 0, stream>>>(
        attn_o, WpT, b_proj, out, nullptr, nullptr, nullptr, 4096, 1024, 1024);
}

// Round 3
// 192.405 us; speedup vs baseline: 2.0559x; 1.5209x over previous
//
#include <hip/hip_runtime.h>
#include <math.h>

typedef __attribute__((ext_vector_type(8))) short bf16x8;
typedef __attribute__((ext_vector_type(4))) short bf16x4;
typedef __attribute__((ext_vector_type(4))) float f32x4;

#define MFMA16(a, b, c) __builtin_amdgcn_mfma_f32_16x16x32_bf16(a, b, c, 0, 0, 0)

#define GLOAD_LDS16(g, l)                                                        \
    __builtin_amdgcn_global_load_lds(                                            \
        (const __attribute__((address_space(1))) void*)(g),                      \
        (__attribute__((address_space(3))) void*)(l), 16, 0, 0)

__device__ __forceinline__ short f2bf(float f) {
    union { float f; unsigned u; } x; x.f = f;
    unsigned r = (x.u + 0x7fffu + ((x.u >> 16) & 1u)) >> 16;
    return (short)r;
}

// ---------------- elementwise fp32 -> bf16 ----------------
__global__ __launch_bounds__(256) void convert_bf16_kernel(
    const float* __restrict__ in, short* __restrict__ out, int n4) {
    int i = blockIdx.x * 256 + threadIdx.x;
    if (i >= n4) return;
    float4 v = ((const float4*)in)[i];
    bf16x4 o;
    o[0] = f2bf(v.x); o[1] = f2bf(v.y); o[2] = f2bf(v.z); o[3] = f2bf(v.w);
    ((bf16x4*)out)[i] = o;
}

// ---------------- transpose + convert: W[K][N] fp32 -> Wt[N][K] bf16 ----------------
__global__ __launch_bounds__(256) void transpose_w_kernel(
    const float* __restrict__ W, short* __restrict__ Wt, int K, int N) {
    __shared__ float tile[32][33];
    int c = threadIdx.x & 31, r0 = threadIdx.x >> 5;
    int n0 = blockIdx.x << 5, k0 = blockIdx.y << 5;
#pragma unroll
    for (int i = 0; i < 4; i++) {
        int r = r0 + i * 8;
        tile[r][c] = W[(long)(k0 + r) * N + n0 + c];
    }
    __syncthreads();
#pragma unroll
    for (int i = 0; i < 4; i++) {
        int r = r0 + i * 8;
        Wt[(long)(n0 + r) * K + k0 + c] = f2bf(tile[c][r]);
    }
}

// ---------------- bf16 GEMM (m97 pattern): C = A[M,K] * Bt[N,K]^T + bias ----------------
// Unpadded [128][64] LDS tiles, XOR-swizzled at 4-word granularity; staged via
// global_load_lds width=16 (wave-uniform LDS base + lane*16). 2-barrier K-loop.
template <int EPI>
__global__ __launch_bounds__(256) void gemm_bt_kernel(
    const short* __restrict__ A, const short* __restrict__ Bt,
    const float* __restrict__ bias, float* __restrict__ outF,
    short* __restrict__ Qb, short* __restrict__ Kb, short* __restrict__ VTb,
    int M, int N, int Kdim) {
    __shared__ __align__(16) short lsA[128 * 64];
    __shared__ __align__(16) short lsB[128 * 64];
    const int tid = threadIdx.x;
    const int lane = tid & 63, l15 = lane & 15, quad = lane >> 4;
    const int w = tid >> 6, wm = w >> 1, wn = w & 1;
    const int m0 = blockIdx.y * 128, n0 = blockIdx.x * 128;
    const int e = l15 & 7;
    // staging geometry: instr i covers rows 8i..8i+7; lane -> row 8i+(lane>>3),
    // logical c4 = (lane&7)^(lane>>3) lands at phys c4 = lane&7 (swizzle c4^=row&7)
    const int lrow = lane >> 3;
    const int lgcol = ((lane & 7) ^ lrow) << 3;  // shorts

    f32x4 acc[4][4];
#pragma unroll
    for (int i = 0; i < 4; i++)
#pragma unroll
        for (int j = 0; j < 4; j++) acc[i][j] = (f32x4){0.f, 0.f, 0.f, 0.f};

    for (int k0 = 0; k0 < Kdim; k0 += 64) {
#pragma unroll
        for (int ii = 0; ii < 4; ii++) {
            const int i = (w << 2) + ii;
            const int grow = (i << 3) + lrow;
            GLOAD_LDS16(&A[(size_t)(m0 + grow) * Kdim + k0 + lgcol], &lsA[i * 512]);
            GLOAD_LDS16(&Bt[(size_t)(n0 + grow) * Kdim + k0 + lgcol], &lsB[i * 512]);
        }
        __syncthreads();
#pragma unroll
        for (int kk = 0; kk < 64; kk += 32) {
            const int kb = kk >> 3;  // 0 or 4
            bf16x8 af[4], bfr[4];
#pragma unroll
            for (int t = 0; t < 4; t++) {
                const int sw = (((kb + quad) ^ e) << 3);
                af[t] = *(const bf16x8*)&lsA[(wm * 64 + t * 16 + l15) * 64 + sw];
                bfr[t] = *(const bf16x8*)&lsB[(wn * 64 + t * 16 + l15) * 64 + sw];
            }
#pragma unroll
            for (int mt = 0; mt < 4; mt++)
#pragma unroll
                for (int nt = 0; nt < 4; nt++)
                    acc[mt][nt] = MFMA16(af[mt], bfr[nt], acc[mt][nt]);
        }
        __syncthreads();
    }

#pragma unroll
    for (int nt = 0; nt < 4; nt++) {
        int nn = n0 + wn * 64 + nt * 16 + l15;
        float bv = bias[nn];
#pragma unroll
        for (int mt = 0; mt < 4; mt++) {
#pragma unroll
            for (int r = 0; r < 4; r++) {
                int mm = m0 + wm * 64 + mt * 16 + quad * 4 + r;
                float val = acc[mt][nt][r] + bv;
                if (EPI == 0) {
                    outF[(long)mm * N + nn] = val;
                } else {
                    int t = nn >> 10, col = nn & 1023, hh = col >> 6, d = col & 63;
                    int b = mm >> 11, s = mm & 2047;
                    int idx = ((b * 16 + hh) * 2048 + s) * 64 + d;
                    if (t == 0) {
                        Qb[idx] = f2bf(val * 0.18033688011112042f);  // 1/8 * log2(e)
                    } else if (t == 1) {
                        Kb[idx] = f2bf(val);
                    } else {
                        VTb[((b * 16 + hh) * 64 + d) * 2048 + s] = f2bf(val);
                    }
                }
            }
        }
    }
}

// ---------------- causal flash attention: 4-wave blocks, shared K/V LDS stream --------
// Block = 64 q rows (wave w: q0 = qt*64+w*16), chunks of 64 keys staged to LDS
// double-buffered (XOR-swizzled, conflict-free fragment reads). S^T = K*Q^T,
// O^T = V^T*P^T (softmax reduction in-lane over 16 regs + 2 shuffles).
__global__ __launch_bounds__(256, 4) void attn_kernel(
    const short* __restrict__ Q, const short* __restrict__ Kb,
    const short* __restrict__ VT, short* __restrict__ Ao) {
    __shared__ __align__(16) short Kt[2][64 * 64];  // 16 KB
    __shared__ __align__(16) short Vt[2][64 * 64];  // 16 KB
    __shared__ __align__(16) short Pt[4][16 * 64];  // 8 KB (per-wave private)
    const int tid = threadIdx.x;
    const int lane = tid & 63, l15 = lane & 15, quad = lane >> 4, w = tid >> 6;
    const int bx = blockIdx.x;
    const int qt = 31 - (bx >> 5);  // heavy q-tiles first
    const int hb = bx & 31;         // b*16 + h
    const int q0 = qt * 64 + w * 16;
    const size_t ho = (size_t)hb * (2048 * 64);
    const short* Qh = Q + ho;
    const short* Kh = Kb + ho;
    const short* Vh = VT + ho;  // [64][2048]
    short* Pw = &Pt[w][0];
    const int e = l15 & 7;

    // staging geometry: thread covers (row=p>>3, logical c4=(p&7)^((p>>3)&7)) for
    // p = tid and tid+256; phys short = row*64 + ((c4^(row&7))<<3) = row*64+(p&7)*8
    const int srow0 = tid >> 3, sc40 = (tid & 7) ^ (srow0 & 7);
    const int srow1 = srow0 + 32, sc41 = (tid & 7) ^ (srow1 & 7);
    const int sdst0 = srow0 * 64 + ((tid & 7) << 3);
    const int sdst1 = srow1 * 64 + ((tid & 7) << 3);

    // Q as B-operand: n = l15 (q), k = quad*8+j (d)
    bf16x8 qf0 = *(const bf16x8*)&Qh[(q0 + l15) * 64 + quad * 8];
    bf16x8 qf1 = *(const bf16x8*)&Qh[(q0 + l15) * 64 + 32 + quad * 8];

    float m = -INFINITY, l = 0.f;
    f32x4 o[4];
#pragma unroll
    for (int dt = 0; dt < 4; dt++) o[dt] = (f32x4){0.f, 0.f, 0.f, 0.f};

    const int nc = qt + 1;  // 64-key chunks

    // stage chunk 0
    *(bf16x8*)&Kt[0][sdst0] = *(const bf16x8*)&Kh[srow0 * 64 + sc40 * 8];
    *(bf16x8*)&Kt[0][sdst1] = *(const bf16x8*)&Kh[srow1 * 64 + sc41 * 8];
    *(bf16x8*)&Vt[0][sdst0] = *(const bf16x8*)&Vh[srow0 * 2048 + sc40 * 8];
    *(bf16x8*)&Vt[0][sdst1] = *(const bf16x8*)&Vh[srow1 * 2048 + sc41 * 8];
    __syncthreads();

    for (int c = 0; c < nc; c++) {
        const short* Kc = &Kt[c & 1][0];
        const short* Vc = &Vt[c & 1][0];
        const bool more = (c + 1 < nc);
        bf16x8 kr0, kr1, vr0, vr1;
        if (more) {
            const int k2 = (c + 1) * 64;
            kr0 = *(const bf16x8*)&Kh[(k2 + srow0) * 64 + sc40 * 8];
            kr1 = *(const bf16x8*)&Kh[(k2 + srow1) * 64 + sc41 * 8];
            vr0 = *(const bf16x8*)&Vh[srow0 * 2048 + k2 + sc40 * 8];
            vr1 = *(const bf16x8*)&Vh[srow1 * 2048 + k2 + sc41 * 8];
        }

        // S^T: A = K tile rows (key), B = Q^T. C/D: col=l15=q, row=quad*4+r=key.
        f32x4 s[4];
#pragma unroll
        for (int t = 0; t < 4; t++) {
            bf16x8 k0f = *(const bf16x8*)&Kc[(t * 16 + l15) * 64 + ((quad ^ e) << 3)];
            bf16x8 k1f = *(const bf16x8*)&Kc[(t * 16 + l15) * 64 + (((4 + quad) ^ e) << 3)];
            f32x4 z = (f32x4){0.f, 0.f, 0.f, 0.f};
            z = MFMA16(k0f, qf0, z);
            z = MFMA16(k1f, qf1, z);
            s[t] = z;
        }

        if (c == nc - 1) {  // diagonal chunk: local key t*16+quad*4+r vs local q w*16+l15
#pragma unroll
            for (int t = 0; t < 4; t++)
#pragma unroll
                for (int r = 0; r < 4; r++)
                    if (t * 16 + quad * 4 + r > w * 16 + l15) s[t][r] = -INFINITY;
        }

        // softmax over 64 keys: in-lane over 16 regs, then xor-16/32 across quads
        float cm = -INFINITY;
#pragma unroll
        for (int t = 0; t < 4; t++)
            cm = fmaxf(cm, fmaxf(fmaxf(s[t][0], s[t][1]), fmaxf(s[t][2], s[t][3])));
        cm = fmaxf(cm, __shfl_xor(cm, 16));
        cm = fmaxf(cm, __shfl_xor(cm, 32));
        const float mn = fmaxf(m, cm);
        const float alpha = __builtin_amdgcn_exp2f(m - mn);
        m = mn;

        float p[4][4];
        float rs = 0.f;
#pragma unroll
        for (int t = 0; t < 4; t++) {
#pragma unroll
            for (int r = 0; r < 4; r++) {
                p[t][r] = __builtin_amdgcn_exp2f(s[t][r] - mn);
                rs += p[t][r];
            }
        }
        rs += __shfl_xor(rs, 16);
        rs += __shfl_xor(rs, 32);
        l = l * alpha + rs;

        // P^T -> per-wave LDS [16 q][64 keys], swizzled; write keys t*16+quad*4..+3
#pragma unroll
        for (int t = 0; t < 4; t++) {
            bf16x4 pw;
#pragma unroll
            for (int r = 0; r < 4; r++) pw[r] = f2bf(p[t][r]);
            *(bf16x4*)&Pw[l15 * 64 + (((2 * t + (quad >> 1)) ^ e) << 3) + ((quad & 1) << 2)] = pw;
        }

#pragma unroll
        for (int dt = 0; dt < 4; dt++) {
            o[dt][0] *= alpha; o[dt][1] *= alpha; o[dt][2] *= alpha; o[dt][3] *= alpha;
        }

        // P^T as B-operand (same-wave ds_write->ds_read; compiler orders via lgkmcnt)
        bf16x8 pf0 = *(const bf16x8*)&Pw[l15 * 64 + ((quad ^ e) << 3)];
        bf16x8 pf1 = *(const bf16x8*)&Pw[l15 * 64 + (((4 + quad) ^ e) << 3)];
#pragma unroll
        for (int dt = 0; dt < 4; dt++) {
            bf16x8 v0f = *(const bf16x8*)&Vc[(dt * 16 + l15) * 64 + ((quad ^ e) << 3)];
            bf16x8 v1f = *(const bf16x8*)&Vc[(dt * 16 + l15) * 64 + (((4 + quad) ^ e) << 3)];
            o[dt] = MFMA16(v0f, pf0, o[dt]);
            o[dt] = MFMA16(v1f, pf1, o[dt]);
        }

        if (more) {
            short* Kn = &Kt[(c + 1) & 1][0];
            short* Vn = &Vt[(c + 1) & 1][0];
            *(bf16x8*)&Kn[sdst0] = kr0;
            *(bf16x8*)&Kn[sdst1] = kr1;
            *(bf16x8*)&Vn[sdst0] = vr0;
            *(bf16x8*)&Vn[sdst1] = vr1;
        }
        __syncthreads();
    }

    // O^T: row=quad*4+r = d within dt tile, col=l15 = q; 4 r-values contiguous in d
    const float rl = 1.f / l;
    const int b = hb >> 4, h = hb & 15;
    const long base = ((long)(b * 2048 + q0 + l15)) * 1024 + h * 64;
#pragma unroll
    for (int dt = 0; dt < 4; dt++) {
        bf16x4 wv;
#pragma unroll
        for (int r = 0; r < 4; r++) wv[r] = f2bf(o[dt][r] * rl);
        *(bf16x4*)&Ao[base + dt * 16 + quad * 4] = wv;
    }
}

extern "C" void kernel_launch(void* const* d_in, const int* in_sizes, int n_in,
                              void* d_out, int out_size, void* d_ws, size_t ws_size,
                              hipStream_t stream) {
    const float* hs = (const float*)d_in[0];
    const float* W_attn = (const float*)d_in[1];
    const float* b_attn = (const float*)d_in[2];
    const float* W_proj = (const float*)d_in[3];
    const float* b_proj = (const float*)d_in[4];
    float* out = (float*)d_out;

    char* ws = (char*)d_ws;
    short* hs_bf = (short*)ws;                       // 4096x1024 bf16 (8 MB)
    short* attn_o = hs_bf;                           // alias: hs_bf dead after qkv gemm
    short* WaT = (short*)(ws + 8u * 1024 * 1024);    // 3072x1024 bf16 (6 MB)
    short* WpT = (short*)(ws + 14u * 1024 * 1024);   // 1024x1024 bf16 (2 MB)
    short* Qb = (short*)(ws + 16u * 1024 * 1024);    // [2,16,2048,64] bf16 (8 MB)
    short* Kb = (short*)(ws + 24u * 1024 * 1024);    // [2,16,2048,64] bf16 (8 MB)
    short* VTb = (short*)(ws + 32u * 1024 * 1024);   // [2,16,64,2048] bf16 (8 MB)

    convert_bf16_kernel<<<4096, 256, 0, stream>>>(hs, hs_bf, 1048576);
    transpose_w_kernel<<<dim3(96, 32), 256, 0, stream>>>(W_attn, WaT, 1024, 3072);
    transpose_w_kernel<<<dim3(32, 32), 256, 0, stream>>>(W_proj, WpT, 1024, 1024);
    gemm_bt_kernel<1><<<dim3(24, 32), 256, 0, stream>>>(
        hs_bf, WaT, b_attn, nullptr, Qb, Kb, VTb, 4096, 3072, 1024);
    attn_kernel<<<1024, 256, 0, stream>>>(Qb, Kb, VTb, attn_o);
    gemm_bt_kernel<0><<<dim3(8, 32), 256, 0, stream>>>(
        attn_o, WpT, b_proj, out, nullptr, nullptr, nullptr, 4096, 1024, 1024);
}